// Round 2
// baseline (6264.902 us; speedup 1.0000x reference)
//
#include <hip/hip_runtime.h>

#define T_DIM 128
#define B_DIM 256
#define H_DIM 1024
#define E_DIM 1024
#define Z_DIM 512
#define M_ALL (T_DIM * B_DIM)          // 32768 rows in the batched GEMMs
#define PSTRIDE ((size_t)M_ALL * H_DIM)  // plane stride in P

typedef __attribute__((ext_vector_type(8))) short short8;
typedef __attribute__((ext_vector_type(4))) float f32x4;
typedef __attribute__((ext_vector_type(4))) unsigned short u16x4;

__device__ __forceinline__ unsigned short f2bf(float f) {
  unsigned u = __float_as_uint(f);
  u += 0x7fffu + ((u >> 16) & 1u);   // round-to-nearest-even
  return (unsigned short)(u >> 16);
}
__device__ __forceinline__ float sigf(float x) { return 1.0f / (1.0f + __expf(-x)); }
__device__ __forceinline__ float tanhf_(float x) { return 2.0f * sigf(2.0f * x) - 1.0f; }

// ---------------- prep kernels (verified round 1) ----------------

__global__ void cvt_wr(const float* __restrict__ p0, const float* __restrict__ p1,
                       const float* __restrict__ p2, const float* __restrict__ p3,
                       unsigned short* __restrict__ out) {
  size_t i = (size_t)blockIdx.x * 256 + threadIdx.x;
  const float* in = blockIdx.y == 0 ? p0 : blockIdx.y == 1 ? p1 : blockIdx.y == 2 ? p2 : p3;
  out[(size_t)blockIdx.y * (H_DIM * H_DIM) + i] = f2bf(in[i]);
}

__global__ void transpose_k(const float* __restrict__ p0, const float* __restrict__ p1,
                            const float* __restrict__ p2, const float* __restrict__ p3,
                            unsigned short* __restrict__ out, int K, int N) {
  const float* in = blockIdx.z == 0 ? p0 : blockIdx.z == 1 ? p1 : blockIdx.z == 2 ? p2 : p3;
  unsigned short* o = out + (size_t)blockIdx.z * K * N;
  __shared__ float tile[32][33];
  int n0 = blockIdx.x * 32;
  int k0 = blockIdx.y * 32;
#pragma unroll
  for (int i = threadIdx.y; i < 32; i += 8)
    tile[i][threadIdx.x] = in[(size_t)(k0 + i) * N + (n0 + threadIdx.x)];
  __syncthreads();
#pragma unroll
  for (int i = threadIdx.y; i < 32; i += 8)
    o[(size_t)(n0 + i) * K + (k0 + threadIdx.x)] = f2bf(tile[threadIdx.x][i]);
}

__global__ void init_state(const float* __restrict__ hidden, const float* __restrict__ cell,
                           const float* __restrict__ bi, const float* __restrict__ bf,
                           const float* __restrict__ bo, const float* __restrict__ bl,
                           const float* __restrict__ bz, const float* __restrict__ bc,
                           unsigned short* __restrict__ h0, float* __restrict__ c0,
                           float* __restrict__ bias) {
  int i = blockIdx.x * 256 + threadIdx.x;
  const int BH = B_DIM * H_DIM;
  if (i < BH) { h0[i] = f2bf(hidden[i]); return; }
  int j = i - BH;
  if (j < BH) { c0[j] = cell[j]; return; }
  int k = j - BH;
  if (k < 6 * H_DIM) {
    int p = k / H_DIM, q = k - p * H_DIM;
    const float* src = p == 0 ? bi : p == 1 ? bf : p == 2 ? bo : p == 3 ? bc : p == 4 ? bl : bz;
    bias[k] = src[q];
  }
}

// f32 -> bf16, 4 elems/thread
__global__ void cvt_bf16x4(const float* __restrict__ in, unsigned short* __restrict__ out, int n4) {
  int i = blockIdx.x * 256 + threadIdx.x;
  if (i >= n4) return;
  f32x4 v = ((const f32x4*)in)[i];
  u16x4 o;
#pragma unroll
  for (int j = 0; j < 4; ++j) o[j] = f2bf(v[j]);
  ((u16x4*)out)[i] = o;
}

// ---------------- Phase A: batched input projections ----------------
// C = A(bf16 [M][1024]) @ B(bf16 [4096][1024])^T + bias, written plane-major
// into P[4][M_ALL][1024] f32. 128x128 block tile, 4 waves 2x2, wave 64x64.
__global__ __launch_bounds__(256) void gemm_x(
    const unsigned short* __restrict__ A, const unsigned short* __restrict__ B,
    const float* __restrict__ bias, float* __restrict__ P) {
  const int lane = threadIdx.x & 63;
  const int wv = threadIdx.x >> 6;
  const int lr = lane & 15, lg = lane >> 4;
  const int m_wave = blockIdx.y * 128 + (wv >> 1) * 64;
  const int n_wave = blockIdx.x * 128 + (wv & 1) * 64;

  const unsigned short* ar[4];
  const unsigned short* br[4];
#pragma unroll
  for (int i = 0; i < 4; ++i) {
    ar[i] = A + (size_t)(m_wave + i * 16 + lr) * 1024 + lg * 8;
    br[i] = B + (size_t)(n_wave + i * 16 + lr) * 1024 + lg * 8;
  }
  f32x4 acc[4][4] = {};
#pragma unroll 2
  for (int kk = 0; kk < 1024; kk += 32) {
    short8 a[4], b[4];
#pragma unroll
    for (int i = 0; i < 4; ++i) a[i] = *(const short8*)(ar[i] + kk);
#pragma unroll
    for (int i = 0; i < 4; ++i) b[i] = *(const short8*)(br[i] + kk);
#pragma unroll
    for (int mi = 0; mi < 4; ++mi)
#pragma unroll
      for (int ni = 0; ni < 4; ++ni)
        acc[mi][ni] = __builtin_amdgcn_mfma_f32_16x16x32_bf16(a[mi], b[ni], acc[mi][ni], 0, 0, 0);
  }
#pragma unroll
  for (int ni = 0; ni < 4; ++ni) {
    int ng = n_wave + ni * 16 + lr;
    float bv = bias[ng];
    float* outp = P + (size_t)(ng >> 10) * PSTRIDE + (ng & 1023);
#pragma unroll
    for (int mi = 0; mi < 4; ++mi)
#pragma unroll
      for (int j = 0; j < 4; ++j) {
        int m = m_wave + mi * 16 + lg * 4 + j;
        outp[(size_t)m * 1024] = acc[mi][ni][j] + bv;
      }
  }
}

// Fused field GEMM: both l and zhat pre-acts (K=512, shared A), epilogue writes
// lz = sigmoid(l) * tanh(zhat) f32 [M_ALL][1024].
__global__ __launch_bounds__(256) void gemm_lz(
    const unsigned short* __restrict__ A, const unsigned short* __restrict__ Bz,
    const float* __restrict__ bias, float* __restrict__ lz) {
  const int lane = threadIdx.x & 63;
  const int wv = threadIdx.x >> 6;
  const int lr = lane & 15, lg = lane >> 4;
  const int m_wave = blockIdx.y * 128 + (wv >> 1) * 64;
  const int n_wave = blockIdx.x * 128 + (wv & 1) * 64;

  const unsigned short* ar[4];
  const unsigned short* bl[4];
  const unsigned short* bz[4];
#pragma unroll
  for (int i = 0; i < 4; ++i) {
    ar[i] = A + (size_t)(m_wave + i * 16 + lr) * Z_DIM + lg * 8;
    bl[i] = Bz + (size_t)(n_wave + i * 16 + lr) * Z_DIM + lg * 8;
    bz[i] = bl[i] + (size_t)H_DIM * Z_DIM;
  }
  f32x4 accL[4][4] = {};
  f32x4 accZ[4][4] = {};
#pragma unroll 1
  for (int kk = 0; kk < Z_DIM; kk += 32) {
    short8 a[4], l[4], z[4];
#pragma unroll
    for (int i = 0; i < 4; ++i) a[i] = *(const short8*)(ar[i] + kk);
#pragma unroll
    for (int i = 0; i < 4; ++i) l[i] = *(const short8*)(bl[i] + kk);
#pragma unroll
    for (int i = 0; i < 4; ++i) z[i] = *(const short8*)(bz[i] + kk);
#pragma unroll
    for (int mi = 0; mi < 4; ++mi)
#pragma unroll
      for (int ni = 0; ni < 4; ++ni) {
        accL[mi][ni] = __builtin_amdgcn_mfma_f32_16x16x32_bf16(a[mi], l[ni], accL[mi][ni], 0, 0, 0);
        accZ[mi][ni] = __builtin_amdgcn_mfma_f32_16x16x32_bf16(a[mi], z[ni], accZ[mi][ni], 0, 0, 0);
      }
  }
#pragma unroll
  for (int ni = 0; ni < 4; ++ni) {
    int n = n_wave + ni * 16 + lr;
    float bL = bias[4 * H_DIM + n];
    float bZ = bias[5 * H_DIM + n];
#pragma unroll
    for (int mi = 0; mi < 4; ++mi)
#pragma unroll
      for (int j = 0; j < 4; ++j) {
        int m = m_wave + mi * 16 + lg * 4 + j;
        lz[(size_t)m * 1024 + n] = sigf(accL[mi][ni][j] + bL) * tanhf_(accZ[mi][ni][j] + bZ);
      }
  }
}

// ---------------- Phase B: recurrent step (precomputed gates) ----------------
// grid (32 n-tiles, 8 m-tiles), 512 threads = 8 waves: wave = (plane p, K-half).
// Wave computes 32x32 of R_p = h @ Wr_p^T over its 512-wide K slice; LDS combine;
// distributed epilogue streams P/lz/c and writes c, h(bf16), out(f32).
__global__ __launch_bounds__(512) void lstm_step2(
    int t, const unsigned short* __restrict__ Wr,
    const float* __restrict__ P, const float* __restrict__ lz,
    const unsigned short* __restrict__ hin, unsigned short* __restrict__ hout,
    float* __restrict__ cbuf, float* __restrict__ out) {
  __shared__ float fin[2][4][32][32];
  const int lane = threadIdx.x & 63;
  const int wv = threadIdx.x >> 6;   // 0..7
  const int p = wv & 3, kh = wv >> 2;
  const int lr = lane & 15, lg = lane >> 4;
  const int n0 = blockIdx.x * 32, m0 = blockIdx.y * 32;
  const int k0 = kh * 512;

  const unsigned short* a0p = hin + (size_t)(m0 + lr) * H_DIM + k0 + lg * 8;
  const unsigned short* a1p = a0p + 16 * H_DIM;
  const unsigned short* b0p = Wr + ((size_t)p * H_DIM + n0 + lr) * H_DIM + k0 + lg * 8;
  const unsigned short* b1p = b0p + 16 * H_DIM;

  f32x4 acc00 = {}, acc01 = {}, acc10 = {}, acc11 = {};
#pragma unroll 4
  for (int kk = 0; kk < 512; kk += 32) {
    short8 a0 = *(const short8*)(a0p + kk);
    short8 a1 = *(const short8*)(a1p + kk);
    short8 b0 = *(const short8*)(b0p + kk);
    short8 b1 = *(const short8*)(b1p + kk);
    acc00 = __builtin_amdgcn_mfma_f32_16x16x32_bf16(a0, b0, acc00, 0, 0, 0);
    acc01 = __builtin_amdgcn_mfma_f32_16x16x32_bf16(a0, b1, acc01, 0, 0, 0);
    acc10 = __builtin_amdgcn_mfma_f32_16x16x32_bf16(a1, b0, acc10, 0, 0, 0);
    acc11 = __builtin_amdgcn_mfma_f32_16x16x32_bf16(a1, b1, acc11, 0, 0, 0);
  }
#pragma unroll
  for (int j = 0; j < 4; ++j) {
    fin[kh][p][lg * 4 + j][lr] = acc00[j];
    fin[kh][p][lg * 4 + j][16 + lr] = acc01[j];
    fin[kh][p][16 + lg * 4 + j][lr] = acc10[j];
    fin[kh][p][16 + lg * 4 + j][16 + lr] = acc11[j];
  }
  __syncthreads();

#pragma unroll
  for (int i = threadIdx.x; i < 1024; i += 512) {
    int m = i >> 5, n = i & 31;
    size_t idx = (size_t)(m0 + m) * H_DIM + n0 + n;
    size_t pidx = (size_t)t * (B_DIM * H_DIM) + idx;
    float r0 = fin[0][0][m][n] + fin[1][0][m][n];
    float r1 = fin[0][1][m][n] + fin[1][1][m][n];
    float r2 = fin[0][2][m][n] + fin[1][2][m][n];
    float r3 = fin[0][3][m][n] + fin[1][3][m][n];
    float ig = sigf(r0 + P[pidx]);
    float fg = sigf(r1 + P[PSTRIDE + pidx]);
    float og = sigf(r2 + P[2 * PSTRIDE + pidx]);
    float ct = tanhf_(r3 + P[3 * PSTRIDE + pidx]);
    float cn = fg * cbuf[idx] + ig * ct + lz[pidx];
    cbuf[idx] = cn;
    float hn = og * tanhf_(cn);
    hout[idx] = f2bf(hn);
    out[pidx] = hn;
  }
}

// ---------------- fallback fused step (round-1, verified) ----------------
__global__ __launch_bounds__(256) void lstm_step(
    int t, const float* __restrict__ x, const float* __restrict__ z,
    const unsigned short* __restrict__ Wr, const unsigned short* __restrict__ Wx,
    const unsigned short* __restrict__ Wz, const float* __restrict__ bias,
    const unsigned short* __restrict__ hin, unsigned short* __restrict__ hout,
    float* __restrict__ cbuf, float* __restrict__ out) {
  const int lane = threadIdx.x & 63;
  const int wv = threadIdx.x >> 6;
  const int m_base = blockIdx.y * 16;
  const int n_base = blockIdx.x * 64 + wv * 16;
  const int lr = lane & 15;
  const int lg = lane >> 4;
  const int n = n_base + lr;

  f32x4 acc[6];
#pragma unroll
  for (int p = 0; p < 6; ++p) {
    float bv = bias[p * H_DIM + n];
    acc[p] = (f32x4){bv, bv, bv, bv};
  }
  const unsigned short* hrow = hin + (size_t)(m_base + lr) * H_DIM + lg * 8;
  const float* xrow = x + ((size_t)t * B_DIM + m_base + lr) * E_DIM + lg * 8;
  const float* zrow = z + ((size_t)t * B_DIM + m_base + lr) * Z_DIM + lg * 8;
  const unsigned short* wrp = Wr + (size_t)n * H_DIM + lg * 8;
  const unsigned short* wxp = Wx + (size_t)n * E_DIM + lg * 8;
  const unsigned short* wzp = Wz + (size_t)n * Z_DIM + lg * 8;

#pragma unroll 2
  for (int kk = 0; kk < H_DIM; kk += 32) {
    short8 a = *(const short8*)(hrow + kk);
    short8 b0 = *(const short8*)(wrp + kk);
    short8 b1 = *(const short8*)(wrp + 1 * H_DIM * H_DIM + kk);
    short8 b2 = *(const short8*)(wrp + 2 * H_DIM * H_DIM + kk);
    short8 b3 = *(const short8*)(wrp + 3 * H_DIM * H_DIM + kk);
    acc[0] = __builtin_amdgcn_mfma_f32_16x16x32_bf16(a, b0, acc[0], 0, 0, 0);
    acc[1] = __builtin_amdgcn_mfma_f32_16x16x32_bf16(a, b1, acc[1], 0, 0, 0);
    acc[2] = __builtin_amdgcn_mfma_f32_16x16x32_bf16(a, b2, acc[2], 0, 0, 0);
    acc[3] = __builtin_amdgcn_mfma_f32_16x16x32_bf16(a, b3, acc[3], 0, 0, 0);
  }
#pragma unroll 2
  for (int kk = 0; kk < E_DIM; kk += 32) {
    f32x4 x0 = *(const f32x4*)(xrow + kk);
    f32x4 x1 = *(const f32x4*)(xrow + kk + 4);
    short8 a;
#pragma unroll
    for (int j = 0; j < 4; ++j) { a[j] = (short)f2bf(x0[j]); a[j + 4] = (short)f2bf(x1[j]); }
    short8 b0 = *(const short8*)(wxp + kk);
    short8 b1 = *(const short8*)(wxp + 1 * H_DIM * E_DIM + kk);
    short8 b2 = *(const short8*)(wxp + 2 * H_DIM * E_DIM + kk);
    short8 b3 = *(const short8*)(wxp + 3 * H_DIM * E_DIM + kk);
    acc[0] = __builtin_amdgcn_mfma_f32_16x16x32_bf16(a, b0, acc[0], 0, 0, 0);
    acc[1] = __builtin_amdgcn_mfma_f32_16x16x32_bf16(a, b1, acc[1], 0, 0, 0);
    acc[2] = __builtin_amdgcn_mfma_f32_16x16x32_bf16(a, b2, acc[2], 0, 0, 0);
    acc[3] = __builtin_amdgcn_mfma_f32_16x16x32_bf16(a, b3, acc[3], 0, 0, 0);
  }
#pragma unroll 2
  for (int kk = 0; kk < Z_DIM; kk += 32) {
    f32x4 z0 = *(const f32x4*)(zrow + kk);
    f32x4 z1 = *(const f32x4*)(zrow + kk + 4);
    short8 a;
#pragma unroll
    for (int j = 0; j < 4; ++j) { a[j] = (short)f2bf(z0[j]); a[j + 4] = (short)f2bf(z1[j]); }
    short8 b4 = *(const short8*)(wzp + kk);
    short8 b5 = *(const short8*)(wzp + 1 * H_DIM * Z_DIM + kk);
    acc[4] = __builtin_amdgcn_mfma_f32_16x16x32_bf16(a, b4, acc[4], 0, 0, 0);
    acc[5] = __builtin_amdgcn_mfma_f32_16x16x32_bf16(a, b5, acc[5], 0, 0, 0);
  }
#pragma unroll
  for (int j = 0; j < 4; ++j) {
    int b = m_base + lg * 4 + j;
    size_t idx = (size_t)b * H_DIM + n;
    float ig = sigf(acc[0][j]);
    float fg = sigf(acc[1][j]);
    float og = sigf(acc[2][j]);
    float ct = tanhf_(acc[3][j]);
    float lgate = sigf(acc[4][j]);
    float zh = tanhf_(acc[5][j]);
    float cn = fg * cbuf[idx] + ig * ct + lgate * zh;
    cbuf[idx] = cn;
    float hn = og * tanhf_(cn);
    hout[idx] = f2bf(hn);
    out[(size_t)t * (B_DIM * H_DIM) + idx] = hn;
  }
}

// ---------------- launch ----------------

extern "C" void kernel_launch(void* const* d_in, const int* in_sizes, int n_in,
                              void* d_out, int out_size, void* d_ws, size_t ws_size,
                              hipStream_t stream) {
  const float* x = (const float*)d_in[0];
  const float* z = (const float*)d_in[1];
  const float* hidden = (const float*)d_in[2];
  const float* cell = (const float*)d_in[3];
  const float* w_ih = (const float*)d_in[4];
  const float* w_oh = (const float*)d_in[5];
  const float* w_fh = (const float*)d_in[6];
  const float* w_ch = (const float*)d_in[7];
  const float* w_ix = (const float*)d_in[8];
  const float* w_ox = (const float*)d_in[9];
  const float* w_fx = (const float*)d_in[10];
  const float* w_cx = (const float*)d_in[11];
  const float* w_lx = (const float*)d_in[12];
  const float* w_zx = (const float*)d_in[13];
  const float* b_i = (const float*)d_in[14];
  const float* b_f = (const float*)d_in[15];
  const float* b_o = (const float*)d_in[16];
  const float* b_l = (const float*)d_in[17];
  const float* b_z = (const float*)d_in[18];
  const float* b_c = (const float*)d_in[19];

  char* ws = (char*)d_ws;
  unsigned short* Wr = (unsigned short*)(ws + 0);          //  8 MB
  unsigned short* Wx = (unsigned short*)(ws + 8388608);    //  8 MB
  unsigned short* Wz = (unsigned short*)(ws + 16777216);   //  2 MB
  float* bias = (float*)(ws + 18874368);                   // 24 KB
  unsigned short* h0 = (unsigned short*)(ws + 18898944);   // 512 KB
  unsigned short* h1 = (unsigned short*)(ws + 19423232);   // 512 KB
  float* cbuf = (float*)(ws + 19947520);                   //   1 MB
  unsigned short* xbf = (unsigned short*)(ws + 20996096);  //  64 MB
  unsigned short* zbf = (unsigned short*)(ws + 88104960);  //  32 MB
  float* P = (float*)(ws + 121659392);                     // 512 MB [4][32768][1024]
  float* lzb = (float*)(ws + 658530304);                   // 128 MB
  const size_t WS_NEEDED = 792748032ULL;
  float* out = (float*)d_out;

  // shared prep
  cvt_wr<<<dim3(4096, 4), 256, 0, stream>>>(w_ih, w_fh, w_oh, w_ch, Wr);
  transpose_k<<<dim3(32, 32, 4), dim3(32, 8), 0, stream>>>(w_ix, w_fx, w_ox, w_cx, Wx, E_DIM, H_DIM);
  transpose_k<<<dim3(32, 16, 2), dim3(32, 8), 0, stream>>>(w_lx, w_zx, w_lx, w_zx, Wz, Z_DIM, H_DIM);
  init_state<<<2072, 256, 0, stream>>>(hidden, cell, b_i, b_f, b_o, b_l, b_z, b_c, h0, cbuf, bias);

  if (ws_size >= WS_NEEDED) {
    // Phase A: convert activations, batched projections
    cvt_bf16x4<<<(M_ALL * E_DIM / 4 + 255) / 256, 256, 0, stream>>>(x, xbf, M_ALL * E_DIM / 4);
    cvt_bf16x4<<<(M_ALL * Z_DIM / 4 + 255) / 256, 256, 0, stream>>>(z, zbf, M_ALL * Z_DIM / 4);
    gemm_x<<<dim3(32, 256), 256, 0, stream>>>(xbf, Wx, bias, P);
    gemm_lz<<<dim3(8, 256), 256, 0, stream>>>(zbf, Wz, bias, lzb);
    // Phase B: sequential scan, recurrent GEMM only
    for (int t = 0; t < T_DIM; ++t) {
      const unsigned short* hin = (t & 1) ? h1 : h0;
      unsigned short* hout = (t & 1) ? h0 : h1;
      lstm_step2<<<dim3(32, 8), 512, 0, stream>>>(t, Wr, P, lzb, hin, hout, cbuf, out);
    }
  } else {
    // fallback: fully fused per-step path (round 1)
    for (int t = 0; t < T_DIM; ++t) {
      const unsigned short* hin = (t & 1) ? h1 : h0;
      unsigned short* hout = (t & 1) ? h0 : h1;
      lstm_step<<<dim3(16, 16), 256, 0, stream>>>(t, x, z, Wr, Wx, Wz, bias, hin, hout, cbuf, out);
    }
  }
}

// Round 3
// 3839.906 us; speedup vs baseline: 1.6315x; 1.6315x over previous
//
#include <hip/hip_runtime.h>

#define T_DIM 128
#define B_DIM 256
#define H_DIM 1024
#define E_DIM 1024
#define Z_DIM 512

typedef __attribute__((ext_vector_type(8))) short short8;
typedef __attribute__((ext_vector_type(4))) float f32x4;
typedef __attribute__((ext_vector_type(4))) unsigned short u16x4;

__device__ __forceinline__ unsigned short f2bf(float f) {
  unsigned u = __float_as_uint(f);
  u += 0x7fffu + ((u >> 16) & 1u);   // round-to-nearest-even
  return (unsigned short)(u >> 16);
}
__device__ __forceinline__ float sigf(float x) { return 1.0f / (1.0f + __expf(-x)); }
__device__ __forceinline__ float tanhf_(float x) { return 2.0f * sigf(2.0f * x) - 1.0f; }

// ---------------- prep kernels (verified round 1) ----------------

__global__ void cvt_wr(const float* __restrict__ p0, const float* __restrict__ p1,
                       const float* __restrict__ p2, const float* __restrict__ p3,
                       unsigned short* __restrict__ out) {
  size_t i = (size_t)blockIdx.x * 256 + threadIdx.x;
  const float* in = blockIdx.y == 0 ? p0 : blockIdx.y == 1 ? p1 : blockIdx.y == 2 ? p2 : p3;
  out[(size_t)blockIdx.y * (H_DIM * H_DIM) + i] = f2bf(in[i]);
}

__global__ void transpose_k(const float* __restrict__ p0, const float* __restrict__ p1,
                            const float* __restrict__ p2, const float* __restrict__ p3,
                            unsigned short* __restrict__ out, int K, int N) {
  const float* in = blockIdx.z == 0 ? p0 : blockIdx.z == 1 ? p1 : blockIdx.z == 2 ? p2 : p3;
  unsigned short* o = out + (size_t)blockIdx.z * K * N;
  __shared__ float tile[32][33];
  int n0 = blockIdx.x * 32;
  int k0 = blockIdx.y * 32;
#pragma unroll
  for (int i = threadIdx.y; i < 32; i += 8)
    tile[i][threadIdx.x] = in[(size_t)(k0 + i) * N + (n0 + threadIdx.x)];
  __syncthreads();
#pragma unroll
  for (int i = threadIdx.y; i < 32; i += 8)
    o[(size_t)(n0 + i) * K + (k0 + threadIdx.x)] = f2bf(tile[threadIdx.x][i]);
}

__global__ void init_state(const float* __restrict__ hidden, const float* __restrict__ cell,
                           const float* __restrict__ bi, const float* __restrict__ bf,
                           const float* __restrict__ bo, const float* __restrict__ bl,
                           const float* __restrict__ bz, const float* __restrict__ bc,
                           unsigned short* __restrict__ h0, float* __restrict__ c0,
                           float* __restrict__ bias) {
  int i = blockIdx.x * 256 + threadIdx.x;
  const int BH = B_DIM * H_DIM;
  if (i < BH) { h0[i] = f2bf(hidden[i]); return; }
  int j = i - BH;
  if (j < BH) { c0[j] = cell[j]; return; }
  int k = j - BH;
  if (k < 6 * H_DIM) {
    int p = k / H_DIM, q = k - p * H_DIM;
    const float* src = p == 0 ? bi : p == 1 ? bf : p == 2 ? bo : p == 3 ? bc : p == 4 ? bl : bz;
    bias[k] = src[q];
  }
}

// f32 -> bf16, 4 elems/thread
__global__ void cvt_bf16x4(const float* __restrict__ in, unsigned short* __restrict__ out, int n4) {
  int i = blockIdx.x * 256 + threadIdx.x;
  if (i >= n4) return;
  f32x4 v = ((const f32x4*)in)[i];
  u16x4 o;
#pragma unroll
  for (int j = 0; j < 4; ++j) o[j] = f2bf(v[j]);
  ((u16x4*)out)[i] = o;
}

// ---------------- Phase A (chunked): batched input projections ----------------
// C = A(bf16 [Mc][1024]) @ B(bf16 [4096][1024])^T + bias, written plane-major
// into P[4][Mc][1024] f32 (plane stride = pstride elems).
__global__ __launch_bounds__(256) void gemm_x(
    const unsigned short* __restrict__ A, const unsigned short* __restrict__ B,
    const float* __restrict__ bias, float* __restrict__ P, size_t pstride) {
  const int lane = threadIdx.x & 63;
  const int wv = threadIdx.x >> 6;
  const int lr = lane & 15, lg = lane >> 4;
  const int m_wave = blockIdx.y * 128 + (wv >> 1) * 64;
  const int n_wave = blockIdx.x * 128 + (wv & 1) * 64;

  const unsigned short* ar[4];
  const unsigned short* br[4];
#pragma unroll
  for (int i = 0; i < 4; ++i) {
    ar[i] = A + (size_t)(m_wave + i * 16 + lr) * 1024 + lg * 8;
    br[i] = B + (size_t)(n_wave + i * 16 + lr) * 1024 + lg * 8;
  }
  f32x4 acc[4][4] = {};
#pragma unroll 2
  for (int kk = 0; kk < 1024; kk += 32) {
    short8 a[4], b[4];
#pragma unroll
    for (int i = 0; i < 4; ++i) a[i] = *(const short8*)(ar[i] + kk);
#pragma unroll
    for (int i = 0; i < 4; ++i) b[i] = *(const short8*)(br[i] + kk);
#pragma unroll
    for (int mi = 0; mi < 4; ++mi)
#pragma unroll
      for (int ni = 0; ni < 4; ++ni)
        acc[mi][ni] = __builtin_amdgcn_mfma_f32_16x16x32_bf16(a[mi], b[ni], acc[mi][ni], 0, 0, 0);
  }
#pragma unroll
  for (int ni = 0; ni < 4; ++ni) {
    int ng = n_wave + ni * 16 + lr;
    float bv = bias[ng];
    float* outp = P + (size_t)(ng >> 10) * pstride + (ng & 1023);
#pragma unroll
    for (int mi = 0; mi < 4; ++mi)
#pragma unroll
      for (int j = 0; j < 4; ++j) {
        int m = m_wave + mi * 16 + lg * 4 + j;
        outp[(size_t)m * 1024] = acc[mi][ni][j] + bv;
      }
  }
}

// Fused field GEMM chunk: lz = sigmoid(l) * tanh(zhat), f32 [Mc][1024].
__global__ __launch_bounds__(256) void gemm_lz(
    const unsigned short* __restrict__ A, const unsigned short* __restrict__ Bz,
    const float* __restrict__ bias, float* __restrict__ lz) {
  const int lane = threadIdx.x & 63;
  const int wv = threadIdx.x >> 6;
  const int lr = lane & 15, lg = lane >> 4;
  const int m_wave = blockIdx.y * 128 + (wv >> 1) * 64;
  const int n_wave = blockIdx.x * 128 + (wv & 1) * 64;

  const unsigned short* ar[4];
  const unsigned short* bl[4];
  const unsigned short* bz[4];
#pragma unroll
  for (int i = 0; i < 4; ++i) {
    ar[i] = A + (size_t)(m_wave + i * 16 + lr) * Z_DIM + lg * 8;
    bl[i] = Bz + (size_t)(n_wave + i * 16 + lr) * Z_DIM + lg * 8;
    bz[i] = bl[i] + (size_t)H_DIM * Z_DIM;
  }
  f32x4 accL[4][4] = {};
  f32x4 accZ[4][4] = {};
#pragma unroll 1
  for (int kk = 0; kk < Z_DIM; kk += 32) {
    short8 a[4], l[4], z[4];
#pragma unroll
    for (int i = 0; i < 4; ++i) a[i] = *(const short8*)(ar[i] + kk);
#pragma unroll
    for (int i = 0; i < 4; ++i) l[i] = *(const short8*)(bl[i] + kk);
#pragma unroll
    for (int i = 0; i < 4; ++i) z[i] = *(const short8*)(bz[i] + kk);
#pragma unroll
    for (int mi = 0; mi < 4; ++mi)
#pragma unroll
      for (int ni = 0; ni < 4; ++ni) {
        accL[mi][ni] = __builtin_amdgcn_mfma_f32_16x16x32_bf16(a[mi], l[ni], accL[mi][ni], 0, 0, 0);
        accZ[mi][ni] = __builtin_amdgcn_mfma_f32_16x16x32_bf16(a[mi], z[ni], accZ[mi][ni], 0, 0, 0);
      }
  }
#pragma unroll
  for (int ni = 0; ni < 4; ++ni) {
    int n = n_wave + ni * 16 + lr;
    float bL = bias[4 * H_DIM + n];
    float bZ = bias[5 * H_DIM + n];
#pragma unroll
    for (int mi = 0; mi < 4; ++mi)
#pragma unroll
      for (int j = 0; j < 4; ++j) {
        int m = m_wave + mi * 16 + lg * 4 + j;
        lz[(size_t)m * 1024 + n] = sigf(accL[mi][ni][j] + bL) * tanhf_(accZ[mi][ni][j] + bZ);
      }
  }
}

// ---------------- Phase B: recurrent step (precomputed gates) ----------------
// grid (32 n-tiles, 8 m-tiles), 512 threads = 8 waves: wave = (plane p, K-half).
__global__ __launch_bounds__(512) void lstm_step2(
    int t, int tmod, const unsigned short* __restrict__ Wr,
    const float* __restrict__ P, const float* __restrict__ lz, size_t pstride,
    const unsigned short* __restrict__ hin, unsigned short* __restrict__ hout,
    float* __restrict__ cbuf, float* __restrict__ out) {
  __shared__ float fin[2][4][32][33];
  const int lane = threadIdx.x & 63;
  const int wv = threadIdx.x >> 6;   // 0..7
  const int p = wv & 3, kh = wv >> 2;
  const int lr = lane & 15, lg = lane >> 4;
  const int n0 = blockIdx.x * 32, m0 = blockIdx.y * 32;
  const int k0 = kh * 512;

  const unsigned short* a0p = hin + (size_t)(m0 + lr) * H_DIM + k0 + lg * 8;
  const unsigned short* a1p = a0p + 16 * H_DIM;
  const unsigned short* b0p = Wr + ((size_t)p * H_DIM + n0 + lr) * H_DIM + k0 + lg * 8;
  const unsigned short* b1p = b0p + 16 * H_DIM;

  f32x4 acc00 = {}, acc01 = {}, acc10 = {}, acc11 = {};
#pragma unroll 4
  for (int kk = 0; kk < 512; kk += 32) {
    short8 a0 = *(const short8*)(a0p + kk);
    short8 a1 = *(const short8*)(a1p + kk);
    short8 b0 = *(const short8*)(b0p + kk);
    short8 b1 = *(const short8*)(b1p + kk);
    acc00 = __builtin_amdgcn_mfma_f32_16x16x32_bf16(a0, b0, acc00, 0, 0, 0);
    acc01 = __builtin_amdgcn_mfma_f32_16x16x32_bf16(a0, b1, acc01, 0, 0, 0);
    acc10 = __builtin_amdgcn_mfma_f32_16x16x32_bf16(a1, b0, acc10, 0, 0, 0);
    acc11 = __builtin_amdgcn_mfma_f32_16x16x32_bf16(a1, b1, acc11, 0, 0, 0);
  }
#pragma unroll
  for (int j = 0; j < 4; ++j) {
    fin[kh][p][lg * 4 + j][lr] = acc00[j];
    fin[kh][p][lg * 4 + j][16 + lr] = acc01[j];
    fin[kh][p][16 + lg * 4 + j][lr] = acc10[j];
    fin[kh][p][16 + lg * 4 + j][16 + lr] = acc11[j];
  }
  __syncthreads();

#pragma unroll
  for (int i = threadIdx.x; i < 1024; i += 512) {
    int m = i >> 5, n = i & 31;
    size_t idx = (size_t)(m0 + m) * H_DIM + n0 + n;
    size_t pidx = (size_t)tmod * (B_DIM * H_DIM) + idx;
    float r0 = fin[0][0][m][n] + fin[1][0][m][n];
    float r1 = fin[0][1][m][n] + fin[1][1][m][n];
    float r2 = fin[0][2][m][n] + fin[1][2][m][n];
    float r3 = fin[0][3][m][n] + fin[1][3][m][n];
    float ig = sigf(r0 + P[pidx]);
    float fg = sigf(r1 + P[pstride + pidx]);
    float og = sigf(r2 + P[2 * pstride + pidx]);
    float ct = tanhf_(r3 + P[3 * pstride + pidx]);
    float cn = fg * cbuf[idx] + ig * ct + lz[pidx];
    cbuf[idx] = cn;
    float hn = og * tanhf_(cn);
    hout[idx] = f2bf(hn);
    out[(size_t)t * (B_DIM * H_DIM) + idx] = hn;
  }
}

// ---------------- fallback fused step (round-1, verified) ----------------
__global__ __launch_bounds__(256) void lstm_step(
    int t, const float* __restrict__ x, const float* __restrict__ z,
    const unsigned short* __restrict__ Wr, const unsigned short* __restrict__ Wx,
    const unsigned short* __restrict__ Wz, const float* __restrict__ bias,
    const unsigned short* __restrict__ hin, unsigned short* __restrict__ hout,
    float* __restrict__ cbuf, float* __restrict__ out) {
  const int lane = threadIdx.x & 63;
  const int wv = threadIdx.x >> 6;
  const int m_base = blockIdx.y * 16;
  const int n_base = blockIdx.x * 64 + wv * 16;
  const int lr = lane & 15;
  const int lg = lane >> 4;
  const int n = n_base + lr;

  f32x4 acc[6];
#pragma unroll
  for (int p = 0; p < 6; ++p) {
    float bv = bias[p * H_DIM + n];
    acc[p] = (f32x4){bv, bv, bv, bv};
  }
  const unsigned short* hrow = hin + (size_t)(m_base + lr) * H_DIM + lg * 8;
  const float* xrow = x + ((size_t)t * B_DIM + m_base + lr) * E_DIM + lg * 8;
  const float* zrow = z + ((size_t)t * B_DIM + m_base + lr) * Z_DIM + lg * 8;
  const unsigned short* wrp = Wr + (size_t)n * H_DIM + lg * 8;
  const unsigned short* wxp = Wx + (size_t)n * E_DIM + lg * 8;
  const unsigned short* wzp = Wz + (size_t)n * Z_DIM + lg * 8;

#pragma unroll 2
  for (int kk = 0; kk < H_DIM; kk += 32) {
    short8 a = *(const short8*)(hrow + kk);
    short8 b0 = *(const short8*)(wrp + kk);
    short8 b1 = *(const short8*)(wrp + 1 * H_DIM * H_DIM + kk);
    short8 b2 = *(const short8*)(wrp + 2 * H_DIM * H_DIM + kk);
    short8 b3 = *(const short8*)(wrp + 3 * H_DIM * H_DIM + kk);
    acc[0] = __builtin_amdgcn_mfma_f32_16x16x32_bf16(a, b0, acc[0], 0, 0, 0);
    acc[1] = __builtin_amdgcn_mfma_f32_16x16x32_bf16(a, b1, acc[1], 0, 0, 0);
    acc[2] = __builtin_amdgcn_mfma_f32_16x16x32_bf16(a, b2, acc[2], 0, 0, 0);
    acc[3] = __builtin_amdgcn_mfma_f32_16x16x32_bf16(a, b3, acc[3], 0, 0, 0);
  }
#pragma unroll 2
  for (int kk = 0; kk < E_DIM; kk += 32) {
    f32x4 x0 = *(const f32x4*)(xrow + kk);
    f32x4 x1 = *(const f32x4*)(xrow + kk + 4);
    short8 a;
#pragma unroll
    for (int j = 0; j < 4; ++j) { a[j] = (short)f2bf(x0[j]); a[j + 4] = (short)f2bf(x1[j]); }
    short8 b0 = *(const short8*)(wxp + kk);
    short8 b1 = *(const short8*)(wxp + 1 * H_DIM * E_DIM + kk);
    short8 b2 = *(const short8*)(wxp + 2 * H_DIM * E_DIM + kk);
    short8 b3 = *(const short8*)(wxp + 3 * H_DIM * E_DIM + kk);
    acc[0] = __builtin_amdgcn_mfma_f32_16x16x32_bf16(a, b0, acc[0], 0, 0, 0);
    acc[1] = __builtin_amdgcn_mfma_f32_16x16x32_bf16(a, b1, acc[1], 0, 0, 0);
    acc[2] = __builtin_amdgcn_mfma_f32_16x16x32_bf16(a, b2, acc[2], 0, 0, 0);
    acc[3] = __builtin_amdgcn_mfma_f32_16x16x32_bf16(a, b3, acc[3], 0, 0, 0);
  }
#pragma unroll 2
  for (int kk = 0; kk < Z_DIM; kk += 32) {
    f32x4 z0 = *(const f32x4*)(zrow + kk);
    f32x4 z1 = *(const f32x4*)(zrow + kk + 4);
    short8 a;
#pragma unroll
    for (int j = 0; j < 4; ++j) { a[j] = (short)f2bf(z0[j]); a[j + 4] = (short)f2bf(z1[j]); }
    short8 b4 = *(const short8*)(wzp + kk);
    short8 b5 = *(const short8*)(wzp + 1 * H_DIM * Z_DIM + kk);
    acc[4] = __builtin_amdgcn_mfma_f32_16x16x32_bf16(a, b4, acc[4], 0, 0, 0);
    acc[5] = __builtin_amdgcn_mfma_f32_16x16x32_bf16(a, b5, acc[5], 0, 0, 0);
  }
#pragma unroll
  for (int j = 0; j < 4; ++j) {
    int b = m_base + lg * 4 + j;
    size_t idx = (size_t)b * H_DIM + n;
    float ig = sigf(acc[0][j]);
    float fg = sigf(acc[1][j]);
    float og = sigf(acc[2][j]);
    float ct = tanhf_(acc[3][j]);
    float lgate = sigf(acc[4][j]);
    float zh = tanhf_(acc[5][j]);
    float cn = fg * cbuf[idx] + ig * ct + lgate * zh;
    cbuf[idx] = cn;
    float hn = og * tanhf_(cn);
    hout[idx] = f2bf(hn);
    out[(size_t)t * (B_DIM * H_DIM) + idx] = hn;
  }
}

// ---------------- launch ----------------

extern "C" void kernel_launch(void* const* d_in, const int* in_sizes, int n_in,
                              void* d_out, int out_size, void* d_ws, size_t ws_size,
                              hipStream_t stream) {
  const float* x = (const float*)d_in[0];
  const float* z = (const float*)d_in[1];
  const float* hidden = (const float*)d_in[2];
  const float* cell = (const float*)d_in[3];
  const float* w_ih = (const float*)d_in[4];
  const float* w_oh = (const float*)d_in[5];
  const float* w_fh = (const float*)d_in[6];
  const float* w_ch = (const float*)d_in[7];
  const float* w_ix = (const float*)d_in[8];
  const float* w_ox = (const float*)d_in[9];
  const float* w_fx = (const float*)d_in[10];
  const float* w_cx = (const float*)d_in[11];
  const float* w_lx = (const float*)d_in[12];
  const float* w_zx = (const float*)d_in[13];
  const float* b_i = (const float*)d_in[14];
  const float* b_f = (const float*)d_in[15];
  const float* b_o = (const float*)d_in[16];
  const float* b_l = (const float*)d_in[17];
  const float* b_z = (const float*)d_in[18];
  const float* b_c = (const float*)d_in[19];

  char* ws = (char*)d_ws;
  unsigned short* Wr = (unsigned short*)(ws + 0);          //  8 MB
  unsigned short* Wx = (unsigned short*)(ws + 8388608);    //  8 MB
  unsigned short* Wz = (unsigned short*)(ws + 16777216);   //  2 MB
  float* bias = (float*)(ws + 18874368);                   // 24 KB
  unsigned short* h0 = (unsigned short*)(ws + 18898944);   // 512 KB
  unsigned short* h1 = (unsigned short*)(ws + 19423232);   // 512 KB
  float* cbuf = (float*)(ws + 19947520);                   //   1 MB -> ends 20996096
  float* out = (float*)d_out;

  // largest chunk TC (timesteps) fitting workspace: fixed 21 MB + TC * 6.03 MB
  const size_t FIXED = 20996096ULL;
  const size_t PER_T = 6029312ULL;  // xbf 512K + zbf 256K + P 4M + lz 1M
  int TC = 0;
  for (int c = 128; c >= 1; c >>= 1)
    if (FIXED + (size_t)c * PER_T <= ws_size) { TC = c; break; }

  // shared prep
  cvt_wr<<<dim3(4096, 4), 256, 0, stream>>>(w_ih, w_fh, w_oh, w_ch, Wr);
  transpose_k<<<dim3(32, 32, 4), dim3(32, 8), 0, stream>>>(w_ix, w_fx, w_ox, w_cx, Wx, E_DIM, H_DIM);
  transpose_k<<<dim3(32, 16, 2), dim3(32, 8), 0, stream>>>(w_lx, w_zx, w_lx, w_zx, Wz, Z_DIM, H_DIM);
  init_state<<<2072, 256, 0, stream>>>(hidden, cell, b_i, b_f, b_o, b_l, b_z, b_c, h0, cbuf, bias);

  if (TC > 0) {
    unsigned short* xbf = (unsigned short*)(ws + FIXED);
    unsigned short* zbf = (unsigned short*)(ws + FIXED + (size_t)TC * 524288);
    float* P = (float*)(ws + FIXED + (size_t)TC * 786432);
    float* lzb = (float*)(ws + FIXED + (size_t)TC * 4980736);
    const size_t pstride = (size_t)TC * B_DIM * H_DIM;

    for (int t0 = 0; t0 < T_DIM; t0 += TC) {
      int nx4 = TC * B_DIM * E_DIM / 4;
      int nz4 = TC * B_DIM * Z_DIM / 4;
      cvt_bf16x4<<<(nx4 + 255) / 256, 256, 0, stream>>>(x + (size_t)t0 * B_DIM * E_DIM, xbf, nx4);
      cvt_bf16x4<<<(nz4 + 255) / 256, 256, 0, stream>>>(z + (size_t)t0 * B_DIM * Z_DIM, zbf, nz4);
      gemm_x<<<dim3(32, TC * 2), 256, 0, stream>>>(xbf, Wx, bias, P, pstride);
      gemm_lz<<<dim3(8, TC * 2), 256, 0, stream>>>(zbf, Wz, bias, lzb);
      for (int t = t0; t < t0 + TC; ++t) {
        const unsigned short* hin = (t & 1) ? h1 : h0;
        unsigned short* hout = (t & 1) ? h0 : h1;
        lstm_step2<<<dim3(32, 8), 512, 0, stream>>>(t, t - t0, Wr, P, lzb, pstride, hin, hout, cbuf, out);
      }
    }
  } else {
    // fallback: fully fused per-step path (round 1, verified)
    for (int t = 0; t < T_DIM; ++t) {
      const unsigned short* hin = (t & 1) ? h1 : h0;
      unsigned short* hout = (t & 1) ? h0 : h1;
      lstm_step<<<dim3(16, 16), 256, 0, stream>>>(t, x, z, Wr, Wx, Wz, bias, hin, hout, cbuf, out);
    }
  }
}